// Round 1
// baseline (403.745 us; speedup 1.0000x reference)
//
#include <hip/hip_runtime.h>
#include <math.h>

#define LSEQ 8192
#define LC   256
#define NCH  32

// ---------------------------------------------------------------------------
// K1: serpentine gather + LayerNorm over C=96.  out: xn[(b*L+l)*96 + c]
// ---------------------------------------------------------------------------
__global__ __launch_bounds__(256) void k1_serp_ln(const float* __restrict__ x,
    const float* __restrict__ gam, const float* __restrict__ bet,
    float* __restrict__ xn) {
  const int b  = blockIdx.x >> 7;
  const int l0 = (blockIdx.x & 127) << 6;
  __shared__ float xs[96][65];
  __shared__ float mu[64], rs[64];
  const int tid = threadIdx.x;
  for (int idx = tid; idx < 96 * 64; idx += 256) {
    const int c = idx >> 6, l = idx & 63;
    const int lg = l0 + l;
    const int hh = (lg >> 5) & 31, w = lg & 31;
    const int lsrc = (hh & 1) ? (lg + 31 - 2 * w) : lg;
    xs[c][l] = x[(b * 96 + c) * LSEQ + lsrc];
  }
  __syncthreads();
  {
    const int l = tid >> 2, k = tid & 3;
    float s = 0.f, s2 = 0.f;
    for (int c = k; c < 96; c += 4) { const float v = xs[c][l]; s += v; s2 += v * v; }
    s  += __shfl_xor(s, 1);  s  += __shfl_xor(s, 2);
    s2 += __shfl_xor(s2, 1); s2 += __shfl_xor(s2, 2);
    if (k == 0) {
      const float m = s * (1.f / 96.f);
      const float var = s2 * (1.f / 96.f) - m * m;
      mu[l] = m; rs[l] = rsqrtf(var + 1e-5f);
    }
  }
  __syncthreads();
  for (int idx = tid; idx < 64 * 96; idx += 256) {
    const int l = idx / 96, c = idx - l * 96;
    xn[((size_t)b * LSEQ + l0) * 96 + idx] = (xs[c][l] - mu[l]) * rs[l] * gam[c] + bet[c];
  }
}

// ---------------------------------------------------------------------------
// K2: in_proj GEMM  M=16384 x N=384, K=96.  Writes transposed xz[b][e][l];
//     silu applied for e>=192 (the z half).
// ---------------------------------------------------------------------------
__global__ __launch_bounds__(256) void k2_inproj(const float* __restrict__ xn,
    const float* __restrict__ W, float* __restrict__ xz) {
  const int m0 = blockIdx.x << 6;
  const int e0 = blockIdx.y << 6;
  __shared__ float As[96][67];
  __shared__ float Ws[96][67];
  const int tid = threadIdx.x;
  for (int idx = tid; idx < 64 * 96; idx += 256) {
    const int r = idx / 96, k = idx - r * 96;
    As[k][r] = xn[(size_t)m0 * 96 + idx];
    Ws[k][r] = W[(size_t)e0 * 96 + idx];
  }
  __syncthreads();
  const int tx = tid & 15, ty = tid >> 4;
  const int la = tx << 2, ea = ty << 2;
  float acc[4][4] = {};
  for (int k = 0; k < 96; ++k) {
    float av[4], bv[4];
#pragma unroll
    for (int i = 0; i < 4; ++i) av[i] = As[k][la + i];
#pragma unroll
    for (int j = 0; j < 4; ++j) bv[j] = Ws[k][ea + j];
#pragma unroll
    for (int j = 0; j < 4; ++j)
#pragma unroll
      for (int i = 0; i < 4; ++i) acc[j][i] = fmaf(bv[j], av[i], acc[j][i]);
  }
  const int b = m0 >> 13, l0 = m0 & (LSEQ - 1);
  const bool dos = (e0 >= 192);
#pragma unroll
  for (int j = 0; j < 4; ++j) {
    const int e = e0 + ea + j;
    float4 v;
    v.x = acc[j][0]; v.y = acc[j][1]; v.z = acc[j][2]; v.w = acc[j][3];
    if (dos) {
      v.x = v.x / (1.f + __expf(-v.x)); v.y = v.y / (1.f + __expf(-v.y));
      v.z = v.z / (1.f + __expf(-v.z)); v.w = v.w / (1.f + __expf(-v.w));
    }
    *(float4*)(&xz[((size_t)b * 384 + e) * LSEQ + l0 + la]) = v;
  }
}

// ---------------------------------------------------------------------------
// K3: per-direction depthwise causal/anticausal conv + silu + x_proj + dt_proj
//     writes dtdu (float2: dt, dt*xc), t1 (=D*xc), BC interleaved (B_n,C_n).
// ---------------------------------------------------------------------------
__global__ __launch_bounds__(256) void k3_conv_proj(const float* __restrict__ xz,
    const float* __restrict__ cw_f, const float* __restrict__ cb_f,
    const float* __restrict__ xw_f, const float* __restrict__ dtw_f,
    const float* __restrict__ dtb_f, const float* __restrict__ Dp_f,
    const float* __restrict__ cw_b, const float* __restrict__ cb_b,
    const float* __restrict__ xw_b, const float* __restrict__ dtw_b,
    const float* __restrict__ dtb_b, const float* __restrict__ Dp_b,
    float2* __restrict__ dtdu, float* __restrict__ t1, float* __restrict__ BCo) {
  const int dir = blockIdx.z, b = blockIdx.y;
  const int l0 = blockIdx.x << 5;
  const float* cw  = dir ? cw_b  : cw_f;
  const float* cb  = dir ? cb_b  : cb_f;
  const float* xw  = dir ? xw_b  : xw_f;
  const float* dtw = dir ? dtw_b : dtw_f;
  const float* dtb = dir ? dtb_b : dtb_f;
  const float* Dp  = dir ? Dp_b  : Dp_f;
  __shared__ float xcl[192][33];
  __shared__ float xwl[38][194];
  __shared__ float dtwl[1152];
  __shared__ float dbl[32][41];
  const int tid = threadIdx.x;
  for (int idx = tid; idx < 38 * 192; idx += 256) {
    const int r = idx / 192, k = idx - r * 192;
    xwl[r][k] = xw[idx];
  }
  for (int idx = tid; idx < 1152; idx += 256) dtwl[idx] = dtw[idx];
  __syncthreads();
  const int dirb = dir * 2 + b;
  // phase 1: conv + silu
  for (int idx = tid; idx < 192 * 32; idx += 256) {
    const int d = idx >> 5, l = idx & 31;
    const int lg = l0 + l;
    const float* xin = xz + ((size_t)b * 384 + d) * LSEQ;
    float acc = cb[d];
#pragma unroll
    for (int j = 0; j < 4; ++j) {
      const int ls = dir ? (lg + 3 - j) : (lg - 3 + j);
      const float v = ((unsigned)ls < LSEQ) ? xin[ls] : 0.f;
      acc = fmaf(cw[d * 4 + j], v, acc);
    }
    const float xc = acc / (1.f + __expf(-acc));
    xcl[d][l] = xc;
    t1[((size_t)dirb * 192 + d) * LSEQ + lg] = Dp[d] * xc;
  }
  __syncthreads();
  // phase 2: dbl = xc @ x_proj_w^T  (38 outputs per l)
  for (int idx = tid; idx < 32 * 38; idx += 256) {
    const int l = idx / 38, r = idx - l * 38;
    float acc = 0.f;
#pragma unroll 4
    for (int k = 0; k < 192; ++k) acc = fmaf(xcl[k][l], xwl[r][k], acc);
    dbl[l][r] = acc;
  }
  __syncthreads();
  // phase 3: dt = softplus(dbl[:6]@dtw^T + dtb); du = dt*xc
  for (int idx = tid; idx < 192 * 32; idx += 256) {
    const int d = idx >> 5, l = idx & 31;
    float s = dtb[d];
#pragma unroll
    for (int r = 0; r < 6; ++r) s = fmaf(dbl[l][r], dtwl[d * 6 + r], s);
    const float dt = (s > 20.f) ? s : log1pf(__expf(s));
    const float du = dt * xcl[d][l];
    dtdu[((size_t)dirb * 192 + d) * LSEQ + l0 + l] = make_float2(dt, du);
  }
  // phase 4: B/C interleaved  (reads dbl only; no extra barrier needed)
  for (int idx = tid; idx < 1024; idx += 256) {
    const int l = idx >> 5, q = idx & 31, n = q >> 1;
    const float v = (q & 1) ? dbl[l][22 + n] : dbl[l][6 + n];
    BCo[((size_t)dirb * LSEQ + l0 + l) * 32 + q] = v;
  }
}

// ---------------------------------------------------------------------------
// K4: scan pass A — per-chunk decay product P and local end-state (h0=0)
// lane layout: 16 lanes per (d) pair = states n, 4 pairs per wave.
// ---------------------------------------------------------------------------
__global__ __launch_bounds__(256) void k4_scanA(const float2* __restrict__ dtdu,
    const float2* __restrict__ bc2, const float* __restrict__ Al_f,
    const float* __restrict__ Al_b, float* __restrict__ Pb, float* __restrict__ Hb) {
  const int dir = blockIdx.z, b = blockIdx.y;
  const int c = blockIdx.x & 31, dg = blockIdx.x >> 5;
  const int tid = threadIdx.x;
  const int d = (dg << 4) + (tid >> 4), n = tid & 15;
  const int dirb = dir * 2 + b;
  const float Adn = -__expf((dir ? Al_b : Al_f)[d * 16 + n]);
  const float2* dd = dtdu + ((size_t)dirb * 192 + d) * LSEQ;
  const float2* bc = bc2 + ((size_t)dirb * LSEQ) * 16 + n;
  float h = 0.f, P = 1.f;
  const int t0 = c << 8;
  if (dir == 0) {
#pragma unroll 4
    for (int tt = 0; tt < LC; ++tt) {
      const int t = t0 + tt;
      const float2 xv = dd[t];
      const float Bn = bc[(size_t)t * 16].x;
      const float a = __expf(xv.x * Adn);
      h = fmaf(a, h, xv.y * Bn);
      P *= a;
    }
  } else {
#pragma unroll 4
    for (int tt = 0; tt < LC; ++tt) {
      const int t = t0 + (LC - 1) - tt;
      const float2 xv = dd[t];
      const float Bn = bc[(size_t)t * 16].x;
      const float a = __expf(xv.x * Adn);
      h = fmaf(a, h, xv.y * Bn);
      P *= a;
    }
  }
  const int o = ((dirb * 32 + c) * 192 + d) * 16 + n;
  Pb[o] = P; Hb[o] = h;
}

// ---------------------------------------------------------------------------
// K5: scan pass B — chunk-level prefix over 32 chunks, one thread per (dir,b,d,n)
// ---------------------------------------------------------------------------
__global__ __launch_bounds__(256) void k5_scanB(const float* __restrict__ Pb,
    const float* __restrict__ Hb, float* __restrict__ H0) {
  const int g = blockIdx.x * 256 + threadIdx.x;  // 12288 lanes
  const int dirb = g / 3072, dn = g - dirb * 3072;
  const int dir = dirb >> 1;
  const int base = dirb * (32 * 3072) + dn;
  float h = 0.f;
  if (dir == 0) {
    for (int c = 0; c < 32; ++c) {
      const int o = base + c * 3072;
      H0[o] = h;
      h = fmaf(Pb[o], h, Hb[o]);
    }
  } else {
    for (int c = 31; c >= 0; --c) {
      const int o = base + c * 3072;
      H0[o] = h;
      h = fmaf(Pb[o], h, Hb[o]);
    }
  }
}

// ---------------------------------------------------------------------------
// K6: scan pass C — replay chunk with correct h0, y = (h·C + D*xc)*silu(z)
// ---------------------------------------------------------------------------
__global__ __launch_bounds__(256) void k6_scanC(const float2* __restrict__ dtdu,
    const float2* __restrict__ bc2, const float* __restrict__ xz,
    const float* __restrict__ t1, const float* __restrict__ Al_f,
    const float* __restrict__ Al_b, const float* __restrict__ H0,
    float* __restrict__ yf, float* __restrict__ yb) {
  const int dir = blockIdx.z, b = blockIdx.y;
  const int c = blockIdx.x & 31, dg = blockIdx.x >> 5;
  const int tid = threadIdx.x;
  const int d = (dg << 4) + (tid >> 4), n = tid & 15;
  const int dirb = dir * 2 + b;
  const float Adn = -__expf((dir ? Al_b : Al_f)[d * 16 + n]);
  const float2* dd = dtdu + ((size_t)dirb * 192 + d) * LSEQ;
  const float2* bc = bc2 + ((size_t)dirb * LSEQ) * 16 + n;
  const float* sp  = xz + ((size_t)b * 384 + 192 + d) * LSEQ;
  const float* t1p = t1 + ((size_t)dirb * 192 + d) * LSEQ;
  float* yp = (dir ? yb : yf) + ((size_t)b * 192 + d) * LSEQ;
  const int o = ((dirb * 32 + c) * 192 + d) * 16 + n;
  float h = H0[o];
  const int t0 = c << 8;
  if (dir == 0) {
#pragma unroll 4
    for (int tt = 0; tt < LC; ++tt) {
      const int t = t0 + tt;
      const float2 xv = dd[t];
      const float2 v = bc[(size_t)t * 16];
      const float a = __expf(xv.x * Adn);
      h = fmaf(a, h, xv.y * v.x);
      float p = h * v.y;
      p += __shfl_xor(p, 1); p += __shfl_xor(p, 2);
      p += __shfl_xor(p, 4); p += __shfl_xor(p, 8);
      if (n == 0) yp[t] = (p + t1p[t]) * sp[t];
    }
  } else {
#pragma unroll 4
    for (int tt = 0; tt < LC; ++tt) {
      const int t = t0 + (LC - 1) - tt;
      const float2 xv = dd[t];
      const float2 v = bc[(size_t)t * 16];
      const float a = __expf(xv.x * Adn);
      h = fmaf(a, h, xv.y * v.x);
      float p = h * v.y;
      p += __shfl_xor(p, 1); p += __shfl_xor(p, 2);
      p += __shfl_xor(p, 4); p += __shfl_xor(p, 8);
      if (n == 0) yp[t] = (p + t1p[t]) * sp[t];
    }
  }
}

// ---------------------------------------------------------------------------
// K7: out_proj GEMM (K=192, N=96) over yf+yb, then inverse serpentine scatter.
// ---------------------------------------------------------------------------
__global__ __launch_bounds__(256) void k7_outproj(const float* __restrict__ yf,
    const float* __restrict__ yb, const float* __restrict__ W,
    float* __restrict__ out) {
  const int m0 = blockIdx.x << 6;
  const int b = m0 >> 13, l0 = m0 & (LSEQ - 1);
  __shared__ float As[32][66];
  __shared__ float Ws[96][33];
  const int tid = threadIdx.x;
  const int tx = tid & 15, ty = tid >> 4;
  const int la = tx << 2;
  float acc[6][4] = {};
  for (int kc = 0; kc < 192; kc += 32) {
    for (int idx = tid; idx < 32 * 64; idx += 256) {
      const int k = idx >> 6, l = idx & 63;
      const size_t off = ((size_t)b * 192 + kc + k) * LSEQ + l0 + l;
      As[k][l] = yf[off] + yb[off];
    }
    for (int idx = tid; idx < 96 * 32; idx += 256) {
      const int e = idx >> 5, k = idx & 31;
      Ws[e][k] = W[e * 192 + kc + k];
    }
    __syncthreads();
#pragma unroll
    for (int k = 0; k < 32; ++k) {
      const float a0 = As[k][la], a1 = As[k][la + 1], a2 = As[k][la + 2], a3 = As[k][la + 3];
#pragma unroll
      for (int j = 0; j < 6; ++j) {
        const float w = Ws[ty * 6 + j][k];
        acc[j][0] = fmaf(w, a0, acc[j][0]);
        acc[j][1] = fmaf(w, a1, acc[j][1]);
        acc[j][2] = fmaf(w, a2, acc[j][2]);
        acc[j][3] = fmaf(w, a3, acc[j][3]);
      }
    }
    __syncthreads();
  }
#pragma unroll
  for (int j = 0; j < 6; ++j) {
    const int e = ty * 6 + j;
#pragma unroll
    for (int i = 0; i < 4; ++i) {
      const int l = l0 + la + i;
      const int hh = (l >> 5) & 31, w = l & 31;
      const int lp = (hh & 1) ? (l + 31 - 2 * w) : l;
      out[((size_t)b * 96 + e) * LSEQ + lp] = acc[j][i];
    }
  }
}

// ---------------------------------------------------------------------------
extern "C" void kernel_launch(void* const* d_in, const int* in_sizes, int n_in,
                              void* d_out, int out_size, void* d_ws, size_t ws_size,
                              hipStream_t stream) {
  const float* x     = (const float*)d_in[0];
  const float* ln_g  = (const float*)d_in[1];
  const float* ln_b  = (const float*)d_in[2];
  const float* in_w  = (const float*)d_in[3];
  const float* cw_f  = (const float*)d_in[4];
  const float* cb_f  = (const float*)d_in[5];
  const float* xw_f  = (const float*)d_in[6];
  const float* dtw_f = (const float*)d_in[7];
  const float* dtb_f = (const float*)d_in[8];
  const float* Al_f  = (const float*)d_in[9];
  const float* D_f   = (const float*)d_in[10];
  const float* cw_b  = (const float*)d_in[11];
  const float* cb_b  = (const float*)d_in[12];
  const float* xw_b  = (const float*)d_in[13];
  const float* dtw_b = (const float*)d_in[14];
  const float* dtb_b = (const float*)d_in[15];
  const float* Al_b  = (const float*)d_in[16];
  const float* D_b   = (const float*)d_in[17];
  const float* ow    = (const float*)d_in[18];
  float* out = (float*)d_out;

  float* ws = (float*)d_ws;
  float* xn   = ws; ws += (size_t)16384 * 96;        // 1,572,864
  float* xz   = ws; ws += (size_t)2 * 384 * LSEQ;    // 6,291,456
  float* dtdu = ws; ws += (size_t)2 * 2 * 192 * LSEQ * 2;  // 12,582,912
  float* t1   = ws; ws += (size_t)2 * 2 * 192 * LSEQ;      // 6,291,456
  float* BC   = ws; ws += (size_t)2 * 2 * LSEQ * 32;       // 2,097,152
  float* yf   = ws; ws += (size_t)2 * 192 * LSEQ;          // 3,145,728
  float* yb   = ws; ws += (size_t)2 * 192 * LSEQ;          // 3,145,728
  float* Pb   = ws; ws += (size_t)2 * 2 * 32 * 192 * 16;   // 393,216
  float* Hb   = ws; ws += (size_t)2 * 2 * 32 * 192 * 16;   // 393,216
  float* H0   = ws; ws += (size_t)2 * 2 * 32 * 192 * 16;   // 393,216
  // total: 36,306,944 floats = ~145.3 MB

  k1_serp_ln<<<dim3(256), dim3(256), 0, stream>>>(x, ln_g, ln_b, xn);
  k2_inproj<<<dim3(256, 6), dim3(256), 0, stream>>>(xn, in_w, xz);
  k3_conv_proj<<<dim3(256, 2, 2), dim3(256), 0, stream>>>(xz,
      cw_f, cb_f, xw_f, dtw_f, dtb_f, D_f,
      cw_b, cb_b, xw_b, dtw_b, dtb_b, D_b,
      (float2*)dtdu, t1, BC);
  k4_scanA<<<dim3(384, 2, 2), dim3(256), 0, stream>>>((const float2*)dtdu,
      (const float2*)BC, Al_f, Al_b, Pb, Hb);
  k5_scanB<<<dim3(48), dim3(256), 0, stream>>>(Pb, Hb, H0);
  k6_scanC<<<dim3(384, 2, 2), dim3(256), 0, stream>>>((const float2*)dtdu,
      (const float2*)BC, xz, t1, Al_f, Al_b, H0, yf, yb);
  k7_outproj<<<dim3(256), dim3(256), 0, stream>>>(yf, yb, ow, out);
}

// Round 2
// 244.746 us; speedup vs baseline: 1.6496x; 1.6496x over previous
//
#include <hip/hip_runtime.h>
#include <math.h>

#define LSEQ 8192
#define LC   256
#define TS   32
#define NST  8

// ---------------------------------------------------------------------------
// DPP 16-lane reduction (rows of 16 = our d-groups). All-VALU, no LDS pipe.
// xor1 = quad_perm[1,0,3,2]=0xB1, xor2 = quad_perm[2,3,0,1]=0x4E,
// xor8 ≡ row_ror:8=0x128, then xor4 ≡ row_ror:4=0x124 (valid once period-8).
// ---------------------------------------------------------------------------
template<int CTRL>
__device__ __forceinline__ float dpp_add(float x) {
  const int y = __builtin_amdgcn_update_dpp(0, __float_as_int(x), CTRL, 0xF, 0xF, true);
  return x + __int_as_float(y);
}
__device__ __forceinline__ float red16(float x) {
  x = dpp_add<0xB1>(x);
  x = dpp_add<0x4E>(x);
  x = dpp_add<0x128>(x);
  x = dpp_add<0x124>(x);
  return x;
}

// ---------------------------------------------------------------------------
// K1: serpentine gather + LayerNorm over C=96.  out: xn[(b*L+l)*96 + c]
// ---------------------------------------------------------------------------
__global__ __launch_bounds__(256) void k1_serp_ln(const float* __restrict__ x,
    const float* __restrict__ gam, const float* __restrict__ bet,
    float* __restrict__ xn) {
  const int b  = blockIdx.x >> 7;
  const int l0 = (blockIdx.x & 127) << 6;
  __shared__ float xs[96][65];
  __shared__ float mu[64], rs[64];
  const int tid = threadIdx.x;
  for (int idx = tid; idx < 96 * 64; idx += 256) {
    const int c = idx >> 6, l = idx & 63;
    const int lg = l0 + l;
    const int hh = (lg >> 5) & 31, w = lg & 31;
    const int lsrc = (hh & 1) ? (lg + 31 - 2 * w) : lg;
    xs[c][l] = x[(b * 96 + c) * LSEQ + lsrc];
  }
  __syncthreads();
  {
    const int l = tid >> 2, k = tid & 3;
    float s = 0.f, s2 = 0.f;
    for (int c = k; c < 96; c += 4) { const float v = xs[c][l]; s += v; s2 += v * v; }
    s  += __shfl_xor(s, 1);  s  += __shfl_xor(s, 2);
    s2 += __shfl_xor(s2, 1); s2 += __shfl_xor(s2, 2);
    if (k == 0) {
      const float m = s * (1.f / 96.f);
      const float var = s2 * (1.f / 96.f) - m * m;
      mu[l] = m; rs[l] = rsqrtf(var + 1e-5f);
    }
  }
  __syncthreads();
  for (int idx = tid; idx < 64 * 96; idx += 256) {
    const int l = idx / 96, c = idx - l * 96;
    xn[((size_t)b * LSEQ + l0) * 96 + idx] = (xs[c][l] - mu[l]) * rs[l] * gam[c] + bet[c];
  }
}

// ---------------------------------------------------------------------------
// K2: in_proj GEMM  M=16384 x N=384, K=96.  Writes transposed xz[b][e][l];
//     silu applied for e>=192 (the z half).
// ---------------------------------------------------------------------------
__global__ __launch_bounds__(256) void k2_inproj(const float* __restrict__ xn,
    const float* __restrict__ W, float* __restrict__ xz) {
  const int m0 = blockIdx.x << 6;
  const int e0 = blockIdx.y << 6;
  __shared__ float As[96][67];
  __shared__ float Ws[96][67];
  const int tid = threadIdx.x;
  for (int idx = tid; idx < 64 * 96; idx += 256) {
    const int r = idx / 96, k = idx - r * 96;
    As[k][r] = xn[(size_t)m0 * 96 + idx];
    Ws[k][r] = W[(size_t)e0 * 96 + idx];
  }
  __syncthreads();
  const int tx = tid & 15, ty = tid >> 4;
  const int la = tx << 2, ea = ty << 2;
  float acc[4][4] = {};
  for (int k = 0; k < 96; ++k) {
    float av[4], bv[4];
#pragma unroll
    for (int i = 0; i < 4; ++i) av[i] = As[k][la + i];
#pragma unroll
    for (int j = 0; j < 4; ++j) bv[j] = Ws[k][ea + j];
#pragma unroll
    for (int j = 0; j < 4; ++j)
#pragma unroll
      for (int i = 0; i < 4; ++i) acc[j][i] = fmaf(bv[j], av[i], acc[j][i]);
  }
  const int b = m0 >> 13, l0 = m0 & (LSEQ - 1);
  const bool dos = (e0 >= 192);
#pragma unroll
  for (int j = 0; j < 4; ++j) {
    const int e = e0 + ea + j;
    float4 v;
    v.x = acc[j][0]; v.y = acc[j][1]; v.z = acc[j][2]; v.w = acc[j][3];
    if (dos) {
      v.x = v.x / (1.f + __expf(-v.x)); v.y = v.y / (1.f + __expf(-v.y));
      v.z = v.z / (1.f + __expf(-v.z)); v.w = v.w / (1.f + __expf(-v.w));
    }
    *(float4*)(&xz[((size_t)b * 384 + e) * LSEQ + l0 + la]) = v;
  }
}

// ---------------------------------------------------------------------------
// K3: per-direction depthwise causal/anticausal conv + silu + x_proj + dt_proj
// ---------------------------------------------------------------------------
__global__ __launch_bounds__(256) void k3_conv_proj(const float* __restrict__ xz,
    const float* __restrict__ cw_f, const float* __restrict__ cb_f,
    const float* __restrict__ xw_f, const float* __restrict__ dtw_f,
    const float* __restrict__ dtb_f, const float* __restrict__ Dp_f,
    const float* __restrict__ cw_b, const float* __restrict__ cb_b,
    const float* __restrict__ xw_b, const float* __restrict__ dtw_b,
    const float* __restrict__ dtb_b, const float* __restrict__ Dp_b,
    float2* __restrict__ dtdu, float* __restrict__ t1, float* __restrict__ BCo) {
  const int dir = blockIdx.z, b = blockIdx.y;
  const int l0 = blockIdx.x << 5;
  const float* cw  = dir ? cw_b  : cw_f;
  const float* cb  = dir ? cb_b  : cb_f;
  const float* xw  = dir ? xw_b  : xw_f;
  const float* dtw = dir ? dtw_b : dtw_f;
  const float* dtb = dir ? dtb_b : dtb_f;
  const float* Dp  = dir ? Dp_b  : Dp_f;
  __shared__ float xcl[192][33];
  __shared__ float xwl[38][194];
  __shared__ float dtwl[1152];
  __shared__ float dbl[32][41];
  const int tid = threadIdx.x;
  for (int idx = tid; idx < 38 * 192; idx += 256) {
    const int r = idx / 192, k = idx - r * 192;
    xwl[r][k] = xw[idx];
  }
  for (int idx = tid; idx < 1152; idx += 256) dtwl[idx] = dtw[idx];
  __syncthreads();
  const int dirb = dir * 2 + b;
  for (int idx = tid; idx < 192 * 32; idx += 256) {
    const int d = idx >> 5, l = idx & 31;
    const int lg = l0 + l;
    const float* xin = xz + ((size_t)b * 384 + d) * LSEQ;
    float acc = cb[d];
#pragma unroll
    for (int j = 0; j < 4; ++j) {
      const int ls = dir ? (lg + 3 - j) : (lg - 3 + j);
      const float v = ((unsigned)ls < LSEQ) ? xin[ls] : 0.f;
      acc = fmaf(cw[d * 4 + j], v, acc);
    }
    const float xc = acc / (1.f + __expf(-acc));
    xcl[d][l] = xc;
    t1[((size_t)dirb * 192 + d) * LSEQ + lg] = Dp[d] * xc;
  }
  __syncthreads();
  for (int idx = tid; idx < 32 * 38; idx += 256) {
    const int l = idx / 38, r = idx - l * 38;
    float acc = 0.f;
#pragma unroll 4
    for (int k = 0; k < 192; ++k) acc = fmaf(xcl[k][l], xwl[r][k], acc);
    dbl[l][r] = acc;
  }
  __syncthreads();
  for (int idx = tid; idx < 192 * 32; idx += 256) {
    const int d = idx >> 5, l = idx & 31;
    float s = dtb[d];
#pragma unroll
    for (int r = 0; r < 6; ++r) s = fmaf(dbl[l][r], dtwl[d * 6 + r], s);
    const float dt = (s > 20.f) ? s : log1pf(__expf(s));
    const float du = dt * xcl[d][l];
    dtdu[((size_t)dirb * 192 + d) * LSEQ + l0 + l] = make_float2(dt, du);
  }
  for (int idx = tid; idx < 1024; idx += 256) {
    const int l = idx >> 5, q = idx & 31, n = q >> 1;
    const float v = (q & 1) ? dbl[l][22 + n] : dbl[l][6 + n];
    BCo[((size_t)dirb * LSEQ + l0 + l) * 32 + q] = v;
  }
}

// ---------------------------------------------------------------------------
// Scan pass A body: per-chunk decay product P=exp(Adn*Σdt) and local end-state.
// LDS double-buffered sub-tiles of TS=32 t; one barrier per sub-tile.
// ---------------------------------------------------------------------------
template<int DIR>
__device__ __forceinline__ void scanA_body(
    float2 (*sdt)[16][34], float2 (*sbc)[TS][16],
    const float2* __restrict__ dtdu, const float2* __restrict__ bc2,
    const float* __restrict__ Al, float* __restrict__ Pb, float* __restrict__ Hb,
    int b, int c, int dg) {
  const int tid = threadIdx.x;
  const int dl = tid >> 4, n = tid & 15;
  const int dirb = DIR * 2 + b;
  const int d = (dg << 4) + dl;
  const float Adn = -__expf(Al[d * 16 + n]);
  const float2* pdt = dtdu + ((size_t)(dirb * 192) + d) * LSEQ;
  const float2* pbc = bc2 + (size_t)dirb * LSEQ * 16;
  const int c0 = c << 8;
  const int sc = (tid & 15) * 2;   // sdt stage col (float2 units)
  const int br = tid >> 3;         // sbc stage row
  const int bcc = (tid & 7) * 2;   // sbc stage col (float2 units)
  {
    const int t0 = c0 + (DIR ? (NST - 1) : 0) * TS;
    float4 rdt = *(const float4*)&pdt[t0 + sc];
    float4 rbc = *(const float4*)&pbc[(size_t)(t0 + br) * 16 + bcc];
    *(float4*)&sdt[0][dl][sc] = rdt;
    *(float4*)&sbc[0][br][bcc] = rbc;
  }
  __syncthreads();
  float h = 0.f, dts = 0.f;
  int buf = 0;
  for (int i = 0; i < NST; ++i) {
    const int s = DIR ? (NST - 1 - i) : i;
    float4 rdt = make_float4(0.f, 0.f, 0.f, 0.f);
    float4 rbc = make_float4(0.f, 0.f, 0.f, 0.f);
    if (i + 1 < NST) {
      const int t0n = c0 + (DIR ? (s - 1) : (s + 1)) * TS;
      rdt = *(const float4*)&pdt[t0n + sc];
      rbc = *(const float4*)&pbc[(size_t)(t0n + br) * 16 + bcc];
    }
#pragma unroll
    for (int tt = 0; tt < TS; ++tt) {
      const int t = DIR ? (TS - 1 - tt) : tt;
      const float2 xv = sdt[buf][dl][t];
      const float Bn = sbc[buf][t][n].x;
      const float a = __expf(xv.x * Adn);
      h = fmaf(a, h, xv.y * Bn);
      dts += xv.x;
    }
    if (i + 1 < NST) {
      *(float4*)&sdt[buf ^ 1][dl][sc] = rdt;
      *(float4*)&sbc[buf ^ 1][br][bcc] = rbc;
    }
    __syncthreads();
    buf ^= 1;
  }
  const int o = ((dirb * 32 + c) * 192 + d) * 16 + n;
  Pb[o] = __expf(dts * Adn);
  Hb[o] = h;
}

__global__ __launch_bounds__(256) void k4_scanA(const float2* __restrict__ dtdu,
    const float2* __restrict__ bc2, const float* __restrict__ Al_f,
    const float* __restrict__ Al_b, float* __restrict__ Pb, float* __restrict__ Hb) {
  __shared__ float2 sdt[2][16][34];
  __shared__ float2 sbc[2][TS][16];
  const int b = blockIdx.y, c = blockIdx.x & 31, dg = blockIdx.x >> 5;
  if (blockIdx.z == 0) scanA_body<0>(sdt, sbc, dtdu, bc2, Al_f, Pb, Hb, b, c, dg);
  else                 scanA_body<1>(sdt, sbc, dtdu, bc2, Al_b, Pb, Hb, b, c, dg);
}

// ---------------------------------------------------------------------------
// K5: chunk-level prefix over 32 chunks
// ---------------------------------------------------------------------------
__global__ __launch_bounds__(256) void k5_scanB(const float* __restrict__ Pb,
    const float* __restrict__ Hb, float* __restrict__ H0) {
  const int g = blockIdx.x * 256 + threadIdx.x;
  const int dirb = g / 3072, dn = g - dirb * 3072;
  const int dir = dirb >> 1;
  const int base = dirb * (32 * 3072) + dn;
  float h = 0.f;
  if (dir == 0) {
    for (int c = 0; c < 32; ++c) {
      const int o = base + c * 3072;
      H0[o] = h;
      h = fmaf(Pb[o], h, Hb[o]);
    }
  } else {
    for (int c = 31; c >= 0; --c) {
      const int o = base + c * 3072;
      H0[o] = h;
      h = fmaf(Pb[o], h, Hb[o]);
    }
  }
}

// ---------------------------------------------------------------------------
// Scan pass C body: replay with correct h0; DPP reduce; register y capture
// (thread n keeps y for t=n and t=16+n) -> coalesced 64B stores.
// ---------------------------------------------------------------------------
template<int DIR>
__device__ __forceinline__ void scanC_body(
    float2 (*sdt)[16][34], float2 (*sbc)[TS][16],
    const float2* __restrict__ dtdu, const float2* __restrict__ bc2,
    const float* __restrict__ xz, const float* __restrict__ t1,
    const float* __restrict__ Al, const float* __restrict__ H0,
    float* __restrict__ yout, int b, int c, int dg) {
  const int tid = threadIdx.x;
  const int dl = tid >> 4, n = tid & 15;
  const int dirb = DIR * 2 + b;
  const int d = (dg << 4) + dl;
  const float Adn = -__expf(Al[d * 16 + n]);
  const float2* pdt = dtdu + ((size_t)(dirb * 192) + d) * LSEQ;
  const float2* pbc = bc2 + (size_t)dirb * LSEQ * 16;
  const float* pt1 = t1 + ((size_t)(dirb * 192) + d) * LSEQ;
  const float* psp = xz + ((size_t)(b * 384) + 192 + d) * LSEQ;
  float* py = yout + ((size_t)(b * 192) + d) * LSEQ;
  const int o = ((dirb * 32 + c) * 192 + d) * 16 + n;
  const int c0 = c << 8;
  const int sc = (tid & 15) * 2;
  const int br = tid >> 3;
  const int bcc = (tid & 7) * 2;
  float h = H0[o];
  const int t00 = c0 + (DIR ? (NST - 1) : 0) * TS;
  {
    float4 rdt = *(const float4*)&pdt[t00 + sc];
    float4 rbc = *(const float4*)&pbc[(size_t)(t00 + br) * 16 + bcc];
    *(float4*)&sdt[0][dl][sc] = rdt;
    *(float4*)&sbc[0][br][bcc] = rbc;
  }
  float ct1a = pt1[t00 + n], ct1b = pt1[t00 + 16 + n];
  float cspa = psp[t00 + n], cspb = psp[t00 + 16 + n];
  __syncthreads();
  int buf = 0;
  for (int i = 0; i < NST; ++i) {
    const int s = DIR ? (NST - 1 - i) : i;
    const int t0 = c0 + s * TS;
    float4 rdt = make_float4(0.f, 0.f, 0.f, 0.f);
    float4 rbc = make_float4(0.f, 0.f, 0.f, 0.f);
    float nt1a = 0.f, nt1b = 0.f, nspa = 0.f, nspb = 0.f;
    if (i + 1 < NST) {
      const int t0n = c0 + (DIR ? (s - 1) : (s + 1)) * TS;
      rdt = *(const float4*)&pdt[t0n + sc];
      rbc = *(const float4*)&pbc[(size_t)(t0n + br) * 16 + bcc];
      nt1a = pt1[t0n + n]; nt1b = pt1[t0n + 16 + n];
      nspa = psp[t0n + n]; nspb = psp[t0n + 16 + n];
    }
    float p0 = 0.f, p1 = 0.f;
#pragma unroll
    for (int tt = 0; tt < TS; ++tt) {
      const int t = DIR ? (TS - 1 - tt) : tt;
      const float2 xv = sdt[buf][dl][t];
      const float2 v = sbc[buf][t][n];
      const float a = __expf(xv.x * Adn);
      h = fmaf(a, h, xv.y * v.x);
      float p = red16(h * v.y);
      if (t < 16) p0 = ((t & 15) == n) ? p : p0;
      else        p1 = ((t & 15) == n) ? p : p1;
    }
    py[t0 + n]      = (p0 + ct1a) * cspa;
    py[t0 + 16 + n] = (p1 + ct1b) * cspb;
    if (i + 1 < NST) {
      *(float4*)&sdt[buf ^ 1][dl][sc] = rdt;
      *(float4*)&sbc[buf ^ 1][br][bcc] = rbc;
      ct1a = nt1a; ct1b = nt1b; cspa = nspa; cspb = nspb;
    }
    __syncthreads();
    buf ^= 1;
  }
}

__global__ __launch_bounds__(256) void k6_scanC(const float2* __restrict__ dtdu,
    const float2* __restrict__ bc2, const float* __restrict__ xz,
    const float* __restrict__ t1, const float* __restrict__ Al_f,
    const float* __restrict__ Al_b, const float* __restrict__ H0,
    float* __restrict__ yf, float* __restrict__ yb) {
  __shared__ float2 sdt[2][16][34];
  __shared__ float2 sbc[2][TS][16];
  const int b = blockIdx.y, c = blockIdx.x & 31, dg = blockIdx.x >> 5;
  if (blockIdx.z == 0)
    scanC_body<0>(sdt, sbc, dtdu, bc2, xz, t1, Al_f, H0, yf, b, c, dg);
  else
    scanC_body<1>(sdt, sbc, dtdu, bc2, xz, t1, Al_b, H0, yb, b, c, dg);
}

// ---------------------------------------------------------------------------
// K7: out_proj GEMM (K=192, N=96) over yf+yb, then inverse serpentine scatter.
// ---------------------------------------------------------------------------
__global__ __launch_bounds__(256) void k7_outproj(const float* __restrict__ yf,
    const float* __restrict__ yb, const float* __restrict__ W,
    float* __restrict__ out) {
  const int m0 = blockIdx.x << 6;
  const int b = m0 >> 13, l0 = m0 & (LSEQ - 1);
  __shared__ float As[32][66];
  __shared__ float Ws[96][33];
  const int tid = threadIdx.x;
  const int tx = tid & 15, ty = tid >> 4;
  const int la = tx << 2;
  float acc[6][4] = {};
  for (int kc = 0; kc < 192; kc += 32) {
    for (int idx = tid; idx < 32 * 64; idx += 256) {
      const int k = idx >> 6, l = idx & 63;
      const size_t off = ((size_t)b * 192 + kc + k) * LSEQ + l0 + l;
      As[k][l] = yf[off] + yb[off];
    }
    for (int idx = tid; idx < 96 * 32; idx += 256) {
      const int e = idx >> 5, k = idx & 31;
      Ws[e][k] = W[e * 192 + kc + k];
    }
    __syncthreads();
#pragma unroll
    for (int k = 0; k < 32; ++k) {
      const float a0 = As[k][la], a1 = As[k][la + 1], a2 = As[k][la + 2], a3 = As[k][la + 3];
#pragma unroll
      for (int j = 0; j < 6; ++j) {
        const float w = Ws[ty * 6 + j][k];
        acc[j][0] = fmaf(w, a0, acc[j][0]);
        acc[j][1] = fmaf(w, a1, acc[j][1]);
        acc[j][2] = fmaf(w, a2, acc[j][2]);
        acc[j][3] = fmaf(w, a3, acc[j][3]);
      }
    }
    __syncthreads();
  }
#pragma unroll
  for (int j = 0; j < 6; ++j) {
    const int e = ty * 6 + j;
#pragma unroll
    for (int i = 0; i < 4; ++i) {
      const int l = l0 + la + i;
      const int hh = (l >> 5) & 31, w = l & 31;
      const int lp = (hh & 1) ? (l + 31 - 2 * w) : l;
      out[((size_t)b * 96 + e) * LSEQ + lp] = acc[j][i];
    }
  }
}

// ---------------------------------------------------------------------------
extern "C" void kernel_launch(void* const* d_in, const int* in_sizes, int n_in,
                              void* d_out, int out_size, void* d_ws, size_t ws_size,
                              hipStream_t stream) {
  const float* x     = (const float*)d_in[0];
  const float* ln_g  = (const float*)d_in[1];
  const float* ln_b  = (const float*)d_in[2];
  const float* in_w  = (const float*)d_in[3];
  const float* cw_f  = (const float*)d_in[4];
  const float* cb_f  = (const float*)d_in[5];
  const float* xw_f  = (const float*)d_in[6];
  const float* dtw_f = (const float*)d_in[7];
  const float* dtb_f = (const float*)d_in[8];
  const float* Al_f  = (const float*)d_in[9];
  const float* D_f   = (const float*)d_in[10];
  const float* cw_b  = (const float*)d_in[11];
  const float* cb_b  = (const float*)d_in[12];
  const float* xw_b  = (const float*)d_in[13];
  const float* dtw_b = (const float*)d_in[14];
  const float* dtb_b = (const float*)d_in[15];
  const float* Al_b  = (const float*)d_in[16];
  const float* D_b   = (const float*)d_in[17];
  const float* ow    = (const float*)d_in[18];
  float* out = (float*)d_out;

  float* ws = (float*)d_ws;
  float* xn   = ws; ws += (size_t)16384 * 96;
  float* xz   = ws; ws += (size_t)2 * 384 * LSEQ;
  float* dtdu = ws; ws += (size_t)2 * 2 * 192 * LSEQ * 2;
  float* t1   = ws; ws += (size_t)2 * 2 * 192 * LSEQ;
  float* BC   = ws; ws += (size_t)2 * 2 * LSEQ * 32;
  float* yf   = ws; ws += (size_t)2 * 192 * LSEQ;
  float* yb   = ws; ws += (size_t)2 * 192 * LSEQ;
  float* Pb   = ws; ws += (size_t)2 * 2 * 32 * 192 * 16;
  float* Hb   = ws; ws += (size_t)2 * 2 * 32 * 192 * 16;
  float* H0   = ws; ws += (size_t)2 * 2 * 32 * 192 * 16;

  k1_serp_ln<<<dim3(256), dim3(256), 0, stream>>>(x, ln_g, ln_b, xn);
  k2_inproj<<<dim3(256, 6), dim3(256), 0, stream>>>(xn, in_w, xz);
  k3_conv_proj<<<dim3(256, 2, 2), dim3(256), 0, stream>>>(xz,
      cw_f, cb_f, xw_f, dtw_f, dtb_f, D_f,
      cw_b, cb_b, xw_b, dtw_b, dtb_b, D_b,
      (float2*)dtdu, t1, BC);
  k4_scanA<<<dim3(384, 2, 2), dim3(256), 0, stream>>>((const float2*)dtdu,
      (const float2*)BC, Al_f, Al_b, Pb, Hb);
  k5_scanB<<<dim3(48), dim3(256), 0, stream>>>(Pb, Hb, H0);
  k6_scanC<<<dim3(384, 2, 2), dim3(256), 0, stream>>>((const float2*)dtdu,
      (const float2*)BC, xz, t1, Al_f, Al_b, H0, yf, yb);
  k7_outproj<<<dim3(256), dim3(256), 0, stream>>>(yf, yb, ow, out);
}